// Round 2
// baseline (1363.333 us; speedup 1.0000x reference)
//
#include <hip/hip_runtime.h>

// StateSpaceModel: y = scan(h = h@A + x@B) @ C,  B=32 L=2048 D=512.
// Inputs/outputs fp32; internal compute bf16 MFMA with fp32 accumulation.
// Chunked parallel scan: local chunk scans (K=8, in-workgroup) -> Kogge-Stone
// over 256 chunk summaries (8 launches, matrix powers A^(8*2^i)) -> recompute
// chunks with true init, fused y = h@C.

using bf16 = __bf16;
typedef __bf16 bf16x8 __attribute__((ext_vector_type(8)));
typedef float  f32x4  __attribute__((ext_vector_type(4)));

constexpr int Dm   = 512;
constexpr int Lseq = 2048;
constexpr int KC   = 8;    // chunk length
constexpr int CH   = 256;  // number of chunks (Lseq / KC)

__device__ __forceinline__ bf16x8 ld8(const bf16* p) {
  return *reinterpret_cast<const bf16x8*>(p);
}
// load 8 fp32, convert to bf16x8
__device__ __forceinline__ bf16x8 ld8f(const float* p) {
  f32x4 lo = *reinterpret_cast<const f32x4*>(p);
  f32x4 hi = *reinterpret_cast<const f32x4*>(p + 4);
  bf16x8 r;
#pragma unroll
  for (int i = 0; i < 4; ++i) { r[i] = (bf16)lo[i]; r[i + 4] = (bf16)hi[i]; }
  return r;
}
__device__ __forceinline__ f32x4 mfma16(bf16x8 a, bf16x8 b, f32x4 c) {
  return __builtin_amdgcn_mfma_f32_16x16x32_bf16(a, b, c, 0, 0, 0);
}

// ---- pack fp32->bf16: Wt[n][k] = W[k][n] for deltaA/deltaB/C, plus Abf=W ----
__global__ __launch_bounds__(256) void kt_pack(
    const float* __restrict__ a, const float* __restrict__ b, const float* __restrict__ c,
    bf16* __restrict__ at, bf16* __restrict__ bt, bf16* __restrict__ ct,
    bf16* __restrict__ abf) {
  int flat = blockIdx.x * 256 + threadIdx.x;
  int n = flat & (Dm - 1);   // fast index -> coalesced read
  int k = flat >> 9;
  const float* s = (blockIdx.y == 0) ? a : (blockIdx.y == 1) ? b : c;
  bf16* d        = (blockIdx.y == 0) ? at : (blockIdx.y == 1) ? bt : ct;
  float v = s[(long)k * Dm + n];
  d[(long)n * Dm + k] = (bf16)v;
  if (blockIdx.y == 0) abf[(long)k * Dm + n] = (bf16)v;
}

// ---- u = x @ deltaB : O[32-row block] = X(fp32) @ Wt^T, O bf16 ----
__global__ __launch_bounds__(512) void kt_gemm_rows(
    const float* __restrict__ X, const bf16* __restrict__ Wt, bf16* __restrict__ O) {
  const int tid = threadIdx.x;
  const int wave = tid >> 6, lane = tid & 63;
  const int quad = lane >> 4, l16 = lane & 15;
  const long rowbase = (long)blockIdx.x * 32;
  const int nbase = wave * 64;
  f32x4 acc[2][4] = {};
  for (int kk = 0; kk < Dm; kk += 32) {
    const int kf = kk + quad * 8;
    bf16x8 a0 = ld8f(X + (rowbase + l16) * Dm + kf);
    bf16x8 a1 = ld8f(X + (rowbase + 16 + l16) * Dm + kf);
#pragma unroll
    for (int nt = 0; nt < 4; ++nt) {
      bf16x8 bw = ld8(Wt + (long)(nbase + nt * 16 + l16) * Dm + kf);
      acc[0][nt] = mfma16(a0, bw, acc[0][nt]);
      acc[1][nt] = mfma16(a1, bw, acc[1][nt]);
    }
  }
#pragma unroll
  for (int mt = 0; mt < 2; ++mt)
#pragma unroll
    for (int nt = 0; nt < 4; ++nt)
#pragma unroll
      for (int r = 0; r < 4; ++r) {
        long m = rowbase + mt * 16 + quad * 4 + r;   // C/D: row = quad*4+reg
        int n = nbase + nt * 16 + l16;               //      col = lane&15
        O[m * Dm + n] = (bf16)acc[mt][nt][r];
      }
}

// ---- S = P @ P (given P, Pt); writes S and S^T for the next squaring ----
__global__ __launch_bounds__(512) void kt_square(
    const bf16* __restrict__ P, const bf16* __restrict__ Pt,
    bf16* __restrict__ S, bf16* __restrict__ St) {
  const int tid = threadIdx.x;
  const int wave = tid >> 6, lane = tid & 63;
  const int quad = lane >> 4, l16 = lane & 15;
  const long rowbase = (long)blockIdx.x * 32;
  const int nbase = wave * 64;
  f32x4 acc[2][4] = {};
  for (int kk = 0; kk < Dm; kk += 32) {
    const int kf = kk + quad * 8;
    bf16x8 a0 = ld8(P + (rowbase + l16) * Dm + kf);
    bf16x8 a1 = ld8(P + (rowbase + 16 + l16) * Dm + kf);
#pragma unroll
    for (int nt = 0; nt < 4; ++nt) {
      bf16x8 bw = ld8(Pt + (long)(nbase + nt * 16 + l16) * Dm + kf);
      acc[0][nt] = mfma16(a0, bw, acc[0][nt]);
      acc[1][nt] = mfma16(a1, bw, acc[1][nt]);
    }
  }
#pragma unroll
  for (int mt = 0; mt < 2; ++mt)
#pragma unroll
    for (int nt = 0; nt < 4; ++nt)
#pragma unroll
      for (int r = 0; r < 4; ++r) {
        long m = rowbase + mt * 16 + quad * 4 + r;
        int n = nbase + nt * 16 + l16;
        float v = acc[mt][nt][r];
        S[m * Dm + n] = (bf16)v;
        St[(long)n * Dm + m] = (bf16)v;
      }
}

// ---- phase 2: per-chunk local scan (zero init), emit summary s_c ----
__global__ __launch_bounds__(512) void kt_scan_local(
    const bf16* __restrict__ u, const bf16* __restrict__ At, bf16* __restrict__ Ssum) {
  __shared__ bf16 h[32 * 520];  // +8 pad keeps 16B alignment, breaks stride
  const int tid = threadIdx.x;
  const int wave = tid >> 6, lane = tid & 63;
  const int quad = lane >> 4, l16 = lane & 15;
  const int c = blockIdx.x;
  const int nbase = wave * 64;
  for (int i = tid; i < 32 * 520; i += 512) h[i] = (bf16)0.f;
  __syncthreads();
  for (int j = 0; j < KC; ++j) {
    const int t = c * KC + j;
    f32x4 acc[2][4] = {};
    for (int kk = 0; kk < Dm; kk += 32) {
      const int kf = kk + quad * 8;
      bf16x8 a0 = ld8(&h[l16 * 520 + kf]);
      bf16x8 a1 = ld8(&h[(16 + l16) * 520 + kf]);
#pragma unroll
      for (int nt = 0; nt < 4; ++nt) {
        bf16x8 bw = ld8(At + (long)(nbase + nt * 16 + l16) * Dm + kf);
        acc[0][nt] = mfma16(a0, bw, acc[0][nt]);
        acc[1][nt] = mfma16(a1, bw, acc[1][nt]);
      }
    }
#pragma unroll
    for (int mt = 0; mt < 2; ++mt)
#pragma unroll
      for (int nt = 0; nt < 4; ++nt)
#pragma unroll
        for (int r = 0; r < 4; ++r) {
          int m = mt * 16 + quad * 4 + r;  // m == batch index (M=32=B)
          int n = nbase + nt * 16 + l16;
          acc[mt][nt][r] += (float)u[((long)m * Lseq + t) * Dm + n];
        }
    __syncthreads();
#pragma unroll
    for (int mt = 0; mt < 2; ++mt)
#pragma unroll
      for (int nt = 0; nt < 4; ++nt)
#pragma unroll
        for (int r = 0; r < 4; ++r) {
          int m = mt * 16 + quad * 4 + r;
          int n = nbase + nt * 16 + l16;
          h[m * 520 + n] = (bf16)acc[mt][nt][r];
        }
    __syncthreads();
  }
  const int row = tid >> 4;
  const int colb = (tid & 15) * 32;
#pragma unroll
  for (int i = 0; i < 4; ++i) {
    bf16x8 v = ld8(&h[row * 520 + colb + i * 8]);
    *reinterpret_cast<bf16x8*>(Ssum + ((long)c * 32 + row) * Dm + colb + i * 8) = v;
  }
}

// ---- Kogge-Stone round: Hout[c] = Hin[c] + Hin[c-shift] @ Qt^T ----
__global__ __launch_bounds__(512) void kt_ks(
    const bf16* __restrict__ Hin, bf16* __restrict__ Hout,
    const bf16* __restrict__ Qt, int shift) {
  const int c = blockIdx.x;
  const int tid = threadIdx.x;
  if (c < shift) {
    const bf16* s = Hin + (long)c * 32 * Dm;
    bf16* d = Hout + (long)c * 32 * Dm;
    for (int i = tid * 8; i < 32 * Dm; i += 512 * 8)
      *reinterpret_cast<bf16x8*>(d + i) = ld8(s + i);
    return;
  }
  const int wave = tid >> 6, lane = tid & 63;
  const int quad = lane >> 4, l16 = lane & 15;
  const int nbase = wave * 64;
  const bf16* Xs = Hin + (long)(c - shift) * 32 * Dm;
  const bf16* Ac = Hin + (long)c * 32 * Dm;
  bf16* Od = Hout + (long)c * 32 * Dm;
  f32x4 acc[2][4] = {};
  for (int kk = 0; kk < Dm; kk += 32) {
    const int kf = kk + quad * 8;
    bf16x8 a0 = ld8(Xs + (long)l16 * Dm + kf);
    bf16x8 a1 = ld8(Xs + (long)(16 + l16) * Dm + kf);
#pragma unroll
    for (int nt = 0; nt < 4; ++nt) {
      bf16x8 bw = ld8(Qt + (long)(nbase + nt * 16 + l16) * Dm + kf);
      acc[0][nt] = mfma16(a0, bw, acc[0][nt]);
      acc[1][nt] = mfma16(a1, bw, acc[1][nt]);
    }
  }
#pragma unroll
  for (int mt = 0; mt < 2; ++mt)
#pragma unroll
    for (int nt = 0; nt < 4; ++nt)
#pragma unroll
      for (int r = 0; r < 4; ++r) {
        int m = mt * 16 + quad * 4 + r;
        int n = nbase + nt * 16 + l16;
        float v = acc[mt][nt][r] + (float)Ac[(long)m * Dm + n];
        Od[(long)m * Dm + n] = (bf16)v;
      }
}

// ---- phase 4: rescan chunk from true init H_{c-1}, fused y = h @ C (fp32 out) ----
__global__ __launch_bounds__(512) void kt_scan_out(
    const bf16* __restrict__ u, const bf16* __restrict__ At,
    const bf16* __restrict__ Ct, const bf16* __restrict__ Hfin,
    float* __restrict__ y) {
  __shared__ bf16 h[32 * 520];
  const int tid = threadIdx.x;
  const int wave = tid >> 6, lane = tid & 63;
  const int quad = lane >> 4, l16 = lane & 15;
  const int c = blockIdx.x;
  const int nbase = wave * 64;
  if (c == 0) {
    for (int i = tid; i < 32 * 520; i += 512) h[i] = (bf16)0.f;
  } else {
    const int row = tid >> 4;
    const int colb = (tid & 15) * 32;
    const bf16* s = Hfin + (long)(c - 1) * 32 * Dm;
#pragma unroll
    for (int i = 0; i < 4; ++i) {
      bf16x8 v = ld8(s + (long)row * Dm + colb + i * 8);
      *reinterpret_cast<bf16x8*>(&h[row * 520 + colb + i * 8]) = v;
    }
  }
  __syncthreads();
  for (int j = 0; j < KC; ++j) {
    const int t = c * KC + j;
    f32x4 acc[2][4] = {};
    for (int kk = 0; kk < Dm; kk += 32) {
      const int kf = kk + quad * 8;
      bf16x8 a0 = ld8(&h[l16 * 520 + kf]);
      bf16x8 a1 = ld8(&h[(16 + l16) * 520 + kf]);
#pragma unroll
      for (int nt = 0; nt < 4; ++nt) {
        bf16x8 bw = ld8(At + (long)(nbase + nt * 16 + l16) * Dm + kf);
        acc[0][nt] = mfma16(a0, bw, acc[0][nt]);
        acc[1][nt] = mfma16(a1, bw, acc[1][nt]);
      }
    }
#pragma unroll
    for (int mt = 0; mt < 2; ++mt)
#pragma unroll
      for (int nt = 0; nt < 4; ++nt)
#pragma unroll
        for (int r = 0; r < 4; ++r) {
          int m = mt * 16 + quad * 4 + r;
          int n = nbase + nt * 16 + l16;
          acc[mt][nt][r] += (float)u[((long)m * Lseq + t) * Dm + n];
        }
    __syncthreads();
#pragma unroll
    for (int mt = 0; mt < 2; ++mt)
#pragma unroll
      for (int nt = 0; nt < 4; ++nt)
#pragma unroll
        for (int r = 0; r < 4; ++r) {
          int m = mt * 16 + quad * 4 + r;
          int n = nbase + nt * 16 + l16;
          h[m * 520 + n] = (bf16)acc[mt][nt][r];
        }
    __syncthreads();
    // y_t = h @ C
    f32x4 yac[2][4] = {};
    for (int kk = 0; kk < Dm; kk += 32) {
      const int kf = kk + quad * 8;
      bf16x8 a0 = ld8(&h[l16 * 520 + kf]);
      bf16x8 a1 = ld8(&h[(16 + l16) * 520 + kf]);
#pragma unroll
      for (int nt = 0; nt < 4; ++nt) {
        bf16x8 bw = ld8(Ct + (long)(nbase + nt * 16 + l16) * Dm + kf);
        yac[0][nt] = mfma16(a0, bw, yac[0][nt]);
        yac[1][nt] = mfma16(a1, bw, yac[1][nt]);
      }
    }
#pragma unroll
    for (int mt = 0; mt < 2; ++mt)
#pragma unroll
      for (int nt = 0; nt < 4; ++nt)
#pragma unroll
        for (int r = 0; r < 4; ++r) {
          int m = mt * 16 + quad * 4 + r;
          int n = nbase + nt * 16 + l16;
          y[((long)m * Lseq + t) * Dm + n] = yac[mt][nt][r];
        }
  }
}

extern "C" void kernel_launch(void* const* d_in, const int* in_sizes, int n_in,
                              void* d_out, int out_size, void* d_ws, size_t ws_size,
                              hipStream_t stream) {
  const float* x  = (const float*)d_in[0];
  const float* dA = (const float*)d_in[1];
  const float* dB = (const float*)d_in[2];
  const float* Cm = (const float*)d_in[3];
  float* out = (float*)d_out;

  char* w = (char*)d_ws;
  const size_t MATB = (size_t)Dm * Dm * sizeof(bf16);  // 512 KB
  bf16* At  = (bf16*)w; w += MATB;
  bf16* Bt  = (bf16*)w; w += MATB;
  bf16* Ct  = (bf16*)w; w += MATB;
  bf16* Abf = (bf16*)w; w += MATB;
  bf16* pw[10]; bf16* pwT[10];   // level l holds A^(2^(l+1)) and its transpose
  for (int l = 0; l < 10; ++l) { pw[l] = (bf16*)w; w += MATB; pwT[l] = (bf16*)w; w += MATB; }
  bf16* u  = (bf16*)w; w += (size_t)32 * Lseq * Dm * sizeof(bf16);  // 64 MB
  bf16* H0 = (bf16*)w; w += (size_t)CH * 32 * Dm * sizeof(bf16);    // 8 MB
  bf16* H1 = (bf16*)w; w += (size_t)CH * 32 * Dm * sizeof(bf16);    // 8 MB

  // 1. pack + transposes (fp32 -> bf16)
  kt_pack<<<dim3(Dm * Dm / 256, 3), 256, 0, stream>>>(dA, dB, Cm, At, Bt, Ct, Abf);
  // 2. u = x @ deltaB
  kt_gemm_rows<<<(32 * Lseq) / 32, 512, 0, stream>>>(x, Bt, u);
  // 3. matrix power chain A^2 .. A^1024 (levels 2..9 = (A^8)^(2^i), i=0..7)
  kt_square<<<Dm / 32, 512, 0, stream>>>(Abf, At, pw[0], pwT[0]);
  for (int l = 1; l < 10; ++l)
    kt_square<<<Dm / 32, 512, 0, stream>>>(pw[l - 1], pwT[l - 1], pw[l], pwT[l]);
  // 4. local chunk scans -> summaries in H0
  kt_scan_local<<<CH, 512, 0, stream>>>(u, At, H0);
  // 5. Kogge-Stone inclusive scan over 256 chunk summaries
  bf16* hin = H0; bf16* hout = H1;
  for (int i = 0; i < 8; ++i) {
    kt_ks<<<CH, 512, 0, stream>>>(hin, hout, pwT[2 + i], 1 << i);
    bf16* tmp = hin; hin = hout; hout = tmp;
  }
  // after 8 rounds final prefixes are back in H0 (== hin)
  // 6. rescan with true init, fused y = h @ C (fp32 output)
  kt_scan_out<<<CH, 512, 0, stream>>>(u, At, Ct, hin, out);
}